// Round 13
// baseline (441.127 us; speedup 1.0000x reference)
//
#include <hip/hip_runtime.h>
#include <stdint.h>

// ---------------------------------------------------------------------------
// TAGConv(3 layers, K=2) + edge-weight norm + MLP link predictor.
// Round 13: k_pred processes 256 pairs/block (4 chunks, C/D gathers pipelined
// under A/B layer-1 MFMA); merged k_sub2 (dst sort + src degree) and k_packX
// (features + weights). SpMM/GEMM unchanged from R12 (422us baseline).
// ---------------------------------------------------------------------------

#define D128 128

typedef __bf16 v8bf __attribute__((ext_vector_type(8)));
typedef float v4f __attribute__((ext_vector_type(4)));
typedef uint32_t v4u __attribute__((ext_vector_type(4)));
typedef unsigned short ushort_t;

union BFU { v4u u; v8bf b; uint4 q; };

__device__ __forceinline__ uint32_t pack_hl(float f) {
  uint32_t hi = __float_as_uint(f) & 0xffff0000u;
  float lo = f - __uint_as_float(hi);
  return hi | (__float_as_uint(lo) >> 16);
}
__device__ __forceinline__ uint32_t f2bf_rn(float f) {
  uint32_t u = __float_as_uint(f);
  return (u + 0x7fffu + ((u >> 16) & 1u)) >> 16;
}
__device__ __forceinline__ float bflo(uint32_t u) { return __uint_as_float(u << 16); }
__device__ __forceinline__ float bfhi(uint32_t u) { return __uint_as_float(u & 0xffff0000u); }
__device__ __forceinline__ uint32_t bfmul2(uint32_t a, uint32_t b) {
  return f2bf_rn(bflo(a) * bflo(b)) | (f2bf_rn(bfhi(a) * bfhi(b)) << 16);
}

// ---------------- sort-based graph build ------------------------------------

__global__ void k_hist2(const int* __restrict__ src, const int* __restrict__ dst,
                        int E, uint32_t* __restrict__ histD,
                        uint32_t* __restrict__ histS) {
  __shared__ uint32_t hd[256], hs[256];
  int t = threadIdx.x;
  hd[t] = 0; hs[t] = 0;
  __syncthreads();
  for (int e = blockIdx.x * 256 + t; e < E; e += gridDim.x * 256) {
    atomicAdd(&hd[((unsigned)dst[e]) >> 8], 1u);
    atomicAdd(&hs[((unsigned)src[e]) >> 8], 1u);
  }
  __syncthreads();
  if (hd[t]) atomicAdd(&histD[t], hd[t]);
  if (hs[t]) atomicAdd(&histS[t], hs[t]);
}

__global__ void k_scan2(const uint32_t* __restrict__ histD,
                        const uint32_t* __restrict__ histS,
                        uint32_t* __restrict__ curD, uint32_t* __restrict__ baseD,
                        uint32_t* __restrict__ curS, uint32_t* __restrict__ baseS,
                        int* __restrict__ rowptr, int N, int E) {
  __shared__ uint32_t ws[4];
  int t = threadIdx.x;
  int lane = t & 63, wid = t >> 6;
  for (int which = 0; which < 2; ++which) {
    uint32_t v = which ? histS[t] : histD[t];
    uint32_t x = v;
#pragma unroll
    for (int d = 1; d < 64; d <<= 1) {
      uint32_t y = (uint32_t)__shfl_up((int)x, d);
      if (lane >= d) x += y;
    }
    if (lane == 63) ws[wid] = x;
    __syncthreads();
    if (t == 0) {
      uint32_t a = 0;
#pragma unroll
      for (int k = 0; k < 4; ++k) { uint32_t tmp = ws[k]; ws[k] = a; a += tmp; }
    }
    __syncthreads();
    uint32_t ex = x - v + ws[wid];
    if (which == 0) {
      curD[t] = ex; baseD[t] = ex;
      if (t == 0) baseD[256] = (uint32_t)E;
    } else {
      curS[t] = ex; baseS[t] = ex;
      if (t == 0) baseS[256] = (uint32_t)E;
    }
    __syncthreads();
  }
  if (t == 0) rowptr[N] = E;
}

// merged partition: one pass over src/dst/w, both bucket sets
__global__ void k_part2(const int* __restrict__ src, const int* __restrict__ dst,
                        const float* __restrict__ w, int E,
                        uint32_t* __restrict__ curD, uint32_t* __restrict__ curS,
                        uint2* __restrict__ bufD, uint2* __restrict__ bufS) {
  __shared__ uint32_t lhD[256], lbD[256], lhS[256], lbS[256];
  int t = threadIdx.x;
  int per = (E + gridDim.x - 1) / gridDim.x;
  int e0 = blockIdx.x * per, e1 = min(e0 + per, E);
  lhD[t] = 0; lhS[t] = 0;
  __syncthreads();
  for (int e = e0 + t; e < e1; e += 256) {
    atomicAdd(&lhD[((unsigned)dst[e]) >> 8], 1u);
    atomicAdd(&lhS[((unsigned)src[e]) >> 8], 1u);
  }
  __syncthreads();
  uint32_t cD = lhD[t], cS = lhS[t];
  lbD[t] = cD ? atomicAdd(&curD[t], cD) : 0u;
  lbS[t] = cS ? atomicAdd(&curS[t], cS) : 0u;
  __syncthreads();
  lhD[t] = 0; lhS[t] = 0;
  __syncthreads();
  for (int e = e0 + t; e < e1; e += 256) {
    int s = src[e], d = dst[e];
    uint32_t wb = __float_as_uint(w[e]);
    uint32_t binD = ((unsigned)d) >> 8;
    uint32_t posD = lbD[binD] + atomicAdd(&lhD[binD], 1u);
    bufD[posD] = make_uint2((((unsigned)d & 255u) << 16) | (unsigned)s, wb);
    uint32_t binS = ((unsigned)s) >> 8;
    uint32_t posS = lbS[binS] + atomicAdd(&lhS[binS], 1u);
    bufS[posS] = make_uint2((unsigned)s, wb);
  }
}

// merged: per-bucket dst counting sort -> CSR, plus src LDS float bins -> deg_out
__global__ void k_sub2(const uint2* __restrict__ bufD, const uint32_t* __restrict__ baseD,
                       const uint2* __restrict__ bufS, const uint32_t* __restrict__ baseS,
                       uint2* __restrict__ esw, int* __restrict__ rowptr,
                       float* __restrict__ deg_out, int N) {
  __shared__ uint32_t lh[256], cur[256], ws4[4];
  __shared__ float facc[256];
  int hb = blockIdx.x, t = threadIdx.x;
  lh[t] = 0;
  facc[t] = 0.f;
  __syncthreads();
  int bS = (int)baseS[hb], eS = (int)baseS[hb + 1];
  for (int i = bS + t; i < eS; i += 256)
    atomicAdd(&facc[bufS[i].x & 255u], __uint_as_float(bufS[i].y));
  int b = (int)baseD[hb], e = (int)baseD[hb + 1];
  for (int i = b + t; i < e; i += 256) atomicAdd(&lh[(bufD[i].x >> 16) & 255u], 1u);
  __syncthreads();
  int s0 = hb * 256 + t;
  if (s0 < N) deg_out[s0] = facc[t];
  uint32_t v = lh[t], x = v;
  int lane = t & 63, wid = t >> 6;
#pragma unroll
  for (int d = 1; d < 64; d <<= 1) {
    uint32_t y = (uint32_t)__shfl_up((int)x, d);
    if (lane >= d) x += y;
  }
  if (lane == 63) ws4[wid] = x;
  __syncthreads();
  if (t == 0) {
    uint32_t a = 0;
#pragma unroll
    for (int k = 0; k < 4; ++k) { uint32_t tmp = ws4[k]; ws4[k] = a; a += tmp; }
  }
  __syncthreads();
  uint32_t ex = x - v + ws4[wid];
  cur[t] = ex;
  if (s0 < N) rowptr[s0] = b + (int)ex;
  __syncthreads();
  for (int i = b + t; i < e; i += 256) {
    uint2 el = bufD[i];
    uint32_t lo = (el.x >> 16) & 255u;
    uint32_t pos = atomicAdd(&cur[lo], 1u);
    esw[b + pos] = make_uint2(el.x & 0xffffu, el.y);
  }
}

__global__ void k_norm(const float* __restrict__ deg_out, const int* __restrict__ rowptr,
                       uint2* __restrict__ esw, int n) {
  int row = blockIdx.x * 4 + (threadIdx.x >> 6);
  if (row >= n) return;
  int lane = threadIdx.x & 63;
  int b0 = rowptr[row];
  int cnt = rowptr[row + 1] - b0;
  if (cnt <= 64) {
    uint32_t key = 0xffffffffu;
    float val = 0.f;
    if (lane < cnt) {
      uint2 e = esw[b0 + lane];
      key = e.x;
      val = __uint_as_float(e.y);
    }
    float s = val;
#pragma unroll
    for (int d = 32; d; d >>= 1) s += __shfl_xor(s, d);
#pragma unroll
    for (int k = 2; k <= 64; k <<= 1) {
#pragma unroll
      for (int j = k >> 1; j > 0; j >>= 1) {
        uint32_t ok = (uint32_t)__shfl_xor((int)key, j);
        float ov = __shfl_xor(val, j);
        bool asc = ((lane & k) == 0);
        bool lower = ((lane & j) == 0);
        bool take_min = (lower == asc);
        bool sw = take_min ? (ok < key) : (ok > key);
        if (sw) { key = ok; val = ov; }
      }
    }
    if (lane < cnt) {
      float dout = deg_out[key];
      float nw = val / sqrtf(fmaxf(dout * s, 1e-12f));
      esw[b0 + lane] = make_uint2(key, __float_as_uint(nw));
    }
  } else {
    float s = 0.f;
    for (int i = lane; i < cnt; i += 64) s += __uint_as_float(esw[b0 + i].y);
#pragma unroll
    for (int d = 32; d; d >>= 1) s += __shfl_xor(s, d);
    for (int i = lane; i < cnt; i += 64) {
      uint2 e = esw[b0 + i];
      float dout = deg_out[e.x];
      float nw = __uint_as_float(e.y) / sqrtf(fmaxf(dout * s, 1e-12f));
      esw[b0 + i] = make_uint2(e.x, __float_as_uint(nw));
    }
  }
}

// ---------------- format conversion (merged features + weights) -------------

__global__ void k_packX(const float* __restrict__ xin, uint32_t* __restrict__ Xp,
                        uint32_t* __restrict__ Xb, int n4,
                        const float* __restrict__ p0, const float* __restrict__ p1,
                        const float* __restrict__ p2, const float* __restrict__ p3,
                        const float* __restrict__ p4, ushort_t* __restrict__ outW) {
  int i = blockIdx.x * 256 + threadIdx.x;
  if (i < n4) {
    float4 f = ((const float4*)xin)[i];
    ((uint4*)Xp)[i] = make_uint4(pack_hl(f.x), pack_hl(f.y), pack_hl(f.z), pack_hl(f.w));
    uint2 b;
    b.x = f2bf_rn(f.x) | (f2bf_rn(f.y) << 16);
    b.y = f2bf_rn(f.z) | (f2bf_rn(f.w) << 16);
    ((uint2*)Xb)[i] = b;
  } else {
    int j = i - n4;
    if (j < 180224) {
      float f;
      if (j < 49152) f = p0[j];
      else if (j < 98304) f = p1[j - 49152];
      else if (j < 147456) f = p2[j - 98304];
      else if (j < 163840) f = p3[j - 147456];
      else f = p4[j - 163840];
      outW[j] = (ushort_t)f2bf_rn(f);
    }
  }
}

// ---------------- SpMM: CSR, 16-deep gather batches -------------------------

__global__ __launch_bounds__(256) void k_spmm(
    const uint32_t* __restrict__ X, uint32_t* __restrict__ Y,
    const uint2* __restrict__ esw, const int* __restrict__ rowptr, int n) {
  int row = blockIdx.x * 4 + (threadIdx.x >> 6);
  if (row >= n) return;
  row = __builtin_amdgcn_readfirstlane(row);
  int lane = threadIdx.x & 63;
  int b0 = rowptr[row];
  int cnt = rowptr[row + 1] - b0;
  const uint2* __restrict__ ep = esw + b0;
  const uint32_t* __restrict__ Xl = X + lane;
  float a0 = 0.f, a1 = 0.f, c0 = 0.f, c1 = 0.f;
  int i = 0;
  for (; i + 16 <= cnt; i += 16) {
    uint2 e[16];
#pragma unroll
    for (int j = 0; j < 16; ++j) e[j] = ep[i + j];
    uint32_t u[16];
#pragma unroll
    for (int j = 0; j < 16; ++j) u[j] = Xl[(size_t)e[j].x * 64];
#pragma unroll
    for (int j = 0; j < 16; j += 2) {
      float w0 = __uint_as_float(e[j].y);
      float w1 = __uint_as_float(e[j + 1].y);
      a0 = fmaf(w0, bflo(u[j]), a0);
      a1 = fmaf(w0, bfhi(u[j]), a1);
      c0 = fmaf(w1, bflo(u[j + 1]), c0);
      c1 = fmaf(w1, bfhi(u[j + 1]), c1);
    }
  }
  for (; i + 4 <= cnt; i += 4) {
    uint2 e[4];
#pragma unroll
    for (int j = 0; j < 4; ++j) e[j] = ep[i + j];
    uint32_t u[4];
#pragma unroll
    for (int j = 0; j < 4; ++j) u[j] = Xl[(size_t)e[j].x * 64];
#pragma unroll
    for (int j = 0; j < 4; j += 2) {
      float w0 = __uint_as_float(e[j].y);
      float w1 = __uint_as_float(e[j + 1].y);
      a0 = fmaf(w0, bflo(u[j]), a0);
      a1 = fmaf(w0, bfhi(u[j]), a1);
      c0 = fmaf(w1, bflo(u[j + 1]), c0);
      c1 = fmaf(w1, bfhi(u[j + 1]), c1);
    }
  }
  for (; i < cnt; ++i) {
    uint2 e = ep[i];
    uint32_t u = Xl[(size_t)e.x * 64];
    float w0 = __uint_as_float(e.y);
    a0 = fmaf(w0, bflo(u), a0);
    a1 = fmaf(w0, bfhi(u), a1);
  }
  Y[(size_t)row * 64 + lane] = f2bf_rn(a0 + c0) | (f2bf_rn(a1 + c1) << 16);
}

// ---------------- MFMA GEMM --------------------------------------------------

__device__ __forceinline__ void build_frags_v(uint4 q0, uint4 q1, v8bf& hi, v8bf& lo) {
  BFU uh, ul;
  uh.u[0] = (q0.x >> 16) | (q0.y & 0xffff0000u);
  uh.u[1] = (q0.z >> 16) | (q0.w & 0xffff0000u);
  uh.u[2] = (q1.x >> 16) | (q1.y & 0xffff0000u);
  uh.u[3] = (q1.z >> 16) | (q1.w & 0xffff0000u);
  ul.u[0] = (q0.x & 0xffffu) | (q0.y << 16);
  ul.u[1] = (q0.z & 0xffffu) | (q0.w << 16);
  ul.u[2] = (q1.x & 0xffffu) | (q1.y << 16);
  ul.u[3] = (q1.z & 0xffffu) | (q1.w << 16);
  hi = uh.b;
  lo = ul.b;
}

__global__ __launch_bounds__(256) void k_gemm(
    const uint32_t* __restrict__ F0hl, const uint32_t* __restrict__ F1b,
    const uint32_t* __restrict__ F2b, const ushort_t* __restrict__ Wb,
    const float* __restrict__ bias, int relu, int M,
    uint32_t* __restrict__ outp, ushort_t* __restrict__ outh,
    float* __restrict__ outf) {
  __shared__ ushort_t Wl[128 * 128];  // 32 KB swizzled
  const int t = threadIdx.x;
  const int lane = t & 63;
  const int wave = t >> 6;
  const int wr = wave >> 1, wc = wave & 1;
  const int row0 = blockIdx.x * 64;
  const int l15 = lane & 15;
  const int kg = lane >> 4;

  int arow[2];
#pragma unroll
  for (int mr = 0; mr < 2; ++mr)
    arow[mr] = min(row0 + wr * 32 + mr * 16 + l15, M - 1);
  int wcol[4];
  float bv[4];
#pragma unroll
  for (int nr = 0; nr < 4; ++nr) {
    wcol[nr] = wc * 64 + nr * 16 + l15;
    bv[nr] = bias[wcol[nr]];
  }

  const uint32_t* __restrict__ F0r0 = F0hl + (size_t)arow[0] * D128 + kg * 8;
  const uint32_t* __restrict__ F0r1 = F0hl + (size_t)arow[1] * D128 + kg * 8;
  const uint32_t* __restrict__ F1r0 = F1b + (size_t)arow[0] * 64 + kg * 4;
  const uint32_t* __restrict__ F1r1 = F1b + (size_t)arow[1] * 64 + kg * 4;
  const uint32_t* __restrict__ F2r0 = F2b + (size_t)arow[0] * 64 + kg * 4;
  const uint32_t* __restrict__ F2r1 = F2b + (size_t)arow[1] * 64 + kg * 4;

  v4f acc[2][4];
#pragma unroll
  for (int mr = 0; mr < 2; ++mr)
#pragma unroll
    for (int nr = 0; nr < 4; ++nr) acc[mr][nr] = (v4f){0.f, 0.f, 0.f, 0.f};

  const int sc = t >> 1;
  const int sh = t & 1;
  const ushort_t* gpW = Wb + (size_t)sc * 384 + sh * 64;
  char* WlBase = (char*)Wl + sc * 256;

  // ---------------- seg0 (hi/lo plane, 2 MFMA per frag) ----------------
  uint4 f0[4][2][2];
#pragma unroll
  for (int kc = 0; kc < 2; ++kc) {
    f0[kc][0][0] = *(const uint4*)(F0r0 + kc * 32);
    f0[kc][0][1] = *(const uint4*)(F0r0 + kc * 32 + 4);
    f0[kc][1][0] = *(const uint4*)(F0r1 + kc * 32);
    f0[kc][1][1] = *(const uint4*)(F0r1 + kc * 32 + 4);
  }
  __syncthreads();
  {
    const ushort_t* gp = gpW;
#pragma unroll
    for (int gi = 0; gi < 8; ++gi) {
      int gg = sh * 8 + gi;
      uint4 v = *(const uint4*)(gp + gi * 8);
      *(uint4*)(WlBase + ((gg ^ (sc & 7)) * 16)) = v;
    }
  }
  __syncthreads();
#pragma unroll
  for (int kc = 0; kc < 4; ++kc) {
    if (kc < 2) {
      f0[kc + 2][0][0] = *(const uint4*)(F0r0 + (kc + 2) * 32);
      f0[kc + 2][0][1] = *(const uint4*)(F0r0 + (kc + 2) * 32 + 4);
      f0[kc + 2][1][0] = *(const uint4*)(F0r1 + (kc + 2) * 32);
      f0[kc + 2][1][1] = *(const uint4*)(F0r1 + (kc + 2) * 32 + 4);
    }
    v8bf ah[2], al[2];
#pragma unroll
    for (int mr = 0; mr < 2; ++mr)
      build_frags_v(f0[kc][mr][0], f0[kc][mr][1], ah[mr], al[mr]);
#pragma unroll
    for (int nr = 0; nr < 4; ++nr) {
      int col = wcol[nr];
      int g = (kc << 2) + kg;
      v8bf bf = *(const v8bf*)((const char*)Wl + col * 256 + ((g ^ (col & 7)) * 16));
#pragma unroll
      for (int mr = 0; mr < 2; ++mr) {
        acc[mr][nr] = __builtin_amdgcn_mfma_f32_16x16x32_bf16(ah[mr], bf, acc[mr][nr], 0, 0, 0);
        acc[mr][nr] = __builtin_amdgcn_mfma_f32_16x16x32_bf16(al[mr], bf, acc[mr][nr], 0, 0, 0);
      }
    }
  }

  // ---------------- seg1, seg2 (bf16 planes, full preload) ----------------
#pragma unroll
  for (int seg = 1; seg < 3; ++seg) {
    const uint32_t* __restrict__ Fr0 = (seg == 1) ? F1r0 : F2r0;
    const uint32_t* __restrict__ Fr1 = (seg == 1) ? F1r1 : F2r1;
    uint4 fb[4][2];
#pragma unroll
    for (int kc = 0; kc < 4; ++kc) {
      fb[kc][0] = *(const uint4*)(Fr0 + kc * 16);
      fb[kc][1] = *(const uint4*)(Fr1 + kc * 16);
    }
    __syncthreads();
    {
      const ushort_t* gp = gpW + seg * 128;
#pragma unroll
      for (int gi = 0; gi < 8; ++gi) {
        int gg = sh * 8 + gi;
        uint4 v = *(const uint4*)(gp + gi * 8);
        *(uint4*)(WlBase + ((gg ^ (sc & 7)) * 16)) = v;
      }
    }
    __syncthreads();
#pragma unroll
    for (int kc = 0; kc < 4; ++kc) {
      v8bf af[2];
      {
        BFU u0, u1;
        u0.q = fb[kc][0];
        u1.q = fb[kc][1];
        af[0] = u0.b;
        af[1] = u1.b;
      }
#pragma unroll
      for (int nr = 0; nr < 4; ++nr) {
        int col = wcol[nr];
        int g = (kc << 2) + kg;
        v8bf bf = *(const v8bf*)((const char*)Wl + col * 256 + ((g ^ (col & 7)) * 16));
#pragma unroll
        for (int mr = 0; mr < 2; ++mr)
          acc[mr][nr] = __builtin_amdgcn_mfma_f32_16x16x32_bf16(af[mr], bf, acc[mr][nr], 0, 0, 0);
      }
    }
  }

  __syncthreads();  // all reads done before (possibly aliased) epilogue writes

#pragma unroll
  for (int mr = 0; mr < 2; ++mr) {
#pragma unroll
    for (int nr = 0; nr < 4; ++nr) {
      v4f a = acc[mr][nr];
#pragma unroll
      for (int r = 0; r < 4; ++r) {
        int row = row0 + wr * 32 + mr * 16 + kg * 4 + r;
        if (row < M) {
          float v = a[r] + bv[nr];
          if (relu) v = fmaxf(v, 0.f);
          size_t o = (size_t)row * D128 + wcol[nr];
          if (outp) outp[o] = pack_hl(v);
          if (outh) outh[o] = (ushort_t)f2bf_rn(v);
          if (outf) outf[o] = v;
        }
      }
    }
  }
}

// ---------------- fused predictor (256 pairs/block, 4 pipelined chunks) -----

__device__ __forceinline__ void pred_load(const uint32_t* __restrict__ Hb, int ia, int ib,
                                          int kg, uint4 (&ga)[4], uint4 (&gb)[4]) {
#pragma unroll
  for (int kc = 0; kc < 4; ++kc) {
    ga[kc] = *(const uint4*)(Hb + (size_t)ia * 64 + kc * 16 + kg * 4);
    gb[kc] = *(const uint4*)(Hb + (size_t)ib * 64 + kc * 16 + kg * 4);
  }
}

__device__ __forceinline__ void pred_cvt(const uint4 (&ga)[4], const uint4 (&gb)[4],
                                         v8bf (&zf)[4]) {
#pragma unroll
  for (int kc = 0; kc < 4; ++kc) {
    BFU z;
    z.u[0] = bfmul2(ga[kc].x, gb[kc].x);
    z.u[1] = bfmul2(ga[kc].y, gb[kc].y);
    z.u[2] = bfmul2(ga[kc].z, gb[kc].z);
    z.u[3] = bfmul2(ga[kc].w, gb[kc].w);
    zf[kc] = z.b;
  }
}

__device__ __forceinline__ void pred_l1(const ushort_t* Wl, const v8bf (&zf)[4],
                                        const float* __restrict__ b1, int l15, int kg,
                                        uint32_t (&pk)[8][2]) {
  v4f acc1[8];
#pragma unroll
  for (int nr = 0; nr < 8; ++nr) acc1[nr] = (v4f){0.f, 0.f, 0.f, 0.f};
#pragma unroll
  for (int kc = 0; kc < 4; ++kc) {
#pragma unroll
    for (int nr = 0; nr < 8; ++nr) {
      int c = nr * 16 + l15;
      int g = 4 * kc + kg;
      v8bf wf = *(const v8bf*)((const char*)Wl + c * 256 + ((g ^ (c & 7)) * 16));
      acc1[nr] = __builtin_amdgcn_mfma_f32_16x16x32_bf16(wf, zf[kc], acc1[nr], 0, 0, 0);
    }
  }
#pragma unroll
  for (int nr = 0; nr < 8; ++nr) {
    float v0 = fmaxf(acc1[nr][0] + b1[nr * 16 + kg * 4 + 0], 0.f);
    float v1 = fmaxf(acc1[nr][1] + b1[nr * 16 + kg * 4 + 1], 0.f);
    float v2 = fmaxf(acc1[nr][2] + b1[nr * 16 + kg * 4 + 2], 0.f);
    float v3 = fmaxf(acc1[nr][3] + b1[nr * 16 + kg * 4 + 3], 0.f);
    pk[nr][0] = f2bf_rn(v0) | (f2bf_rn(v1) << 16);
    pk[nr][1] = f2bf_rn(v2) | (f2bf_rn(v3) << 16);
  }
}

__device__ __forceinline__ float pred_l2(const ushort_t* Wl, const uint32_t (&pk)[8][2],
                                         const float* __restrict__ b2,
                                         const float* __restrict__ w3, int l15, int kg) {
  v4f acc2[8];
#pragma unroll
  for (int nr = 0; nr < 8; ++nr) acc2[nr] = (v4f){0.f, 0.f, 0.f, 0.f};
#pragma unroll
  for (int kc = 0; kc < 4; ++kc) {
    BFU y;
#pragma unroll
    for (int d = 0; d < 4; ++d) {
      int srcLane = l15 + 16 * ((kg & 1) * 2 + (d >> 1));
      uint32_t w0 = (uint32_t)__shfl((int)pk[2 * kc][d & 1], srcLane);
      uint32_t w1 = (uint32_t)__shfl((int)pk[2 * kc + 1][d & 1], srcLane);
      y.u[d] = (kg & 2) ? w1 : w0;
    }
#pragma unroll
    for (int nr = 0; nr < 8; ++nr) {
      int c = nr * 16 + l15;
      int g = 4 * kc + kg;
      v8bf wf = *(const v8bf*)((const char*)Wl + c * 256 + ((g ^ (c & 7)) * 16));
      acc2[nr] = __builtin_amdgcn_mfma_f32_16x16x32_bf16(wf, y.b, acc2[nr], 0, 0, 0);
    }
  }
  float s = 0.f;
#pragma unroll
  for (int nr = 0; nr < 8; ++nr) {
#pragma unroll
    for (int r = 0; r < 4; ++r) {
      int c = nr * 16 + kg * 4 + r;
      s += fmaxf(acc2[nr][r] + b2[c], 0.f) * w3[c];
    }
  }
  s += __shfl_xor(s, 16);
  s += __shfl_xor(s, 32);
  return s;
}

__global__ __launch_bounds__(256) void k_pred(
    const uint32_t* __restrict__ Hb, const int* __restrict__ pos_src,
    const int* __restrict__ pos_dst, const int* __restrict__ neg_src,
    const int* __restrict__ neg_dst, const ushort_t* __restrict__ W1,
    const ushort_t* __restrict__ W2, const float* __restrict__ b1,
    const float* __restrict__ b2, const float* __restrict__ w3,
    const float* __restrict__ b3, int P, float* __restrict__ out) {
  __shared__ ushort_t Wl[128 * 128];
  const int t = threadIdx.x;
  const int lane = t & 63;
  const int wave = t >> 6;
  const int l15 = lane & 15;
  const int kg = lane >> 4;
  const int P2 = 2 * P;
  const int q0 = blockIdx.x * 256 + wave * 16 + l15;

  int ia[4], ib[4];
  bool vv[4];
#pragma unroll
  for (int c = 0; c < 4; ++c) {
    int q = q0 + c * 64;
    vv[c] = q < P2;
    int qc = vv[c] ? q : (P2 - 1);
    ia[c] = (qc < P) ? pos_src[qc] : neg_src[qc - P];
    ib[c] = (qc < P) ? pos_dst[qc] : neg_dst[qc - P];
  }

  const int sc = t >> 1;
  const int sh = t & 1;

  // ---- stage W1 ----
  {
    const ushort_t* gp = W1 + sc * 128 + sh * 64;
#pragma unroll
    for (int gi = 0; gi < 8; ++gi) {
      int gg = sh * 8 + gi;
      uint4 v = *(const uint4*)(gp + gi * 8);
      *(uint4*)((char*)Wl + sc * 256 + ((gg ^ (sc & 7)) * 16)) = v;
    }
  }

  // ---- gather chunks A,B up-front ----
  uint4 gx[4], gy[4], hx[4], hy[4];
  pred_load(Hb, ia[0], ib[0], kg, gx, gy);
  pred_load(Hb, ia[1], ib[1], kg, hx, hy);
  v8bf zfA[4], zfB[4], zfC[4], zfD[4];
  pred_cvt(gx, gy, zfA);
  pred_cvt(hx, hy, zfB);
  __syncthreads();

  // ---- layer 1 pipelined with chunk C,D gathers ----
  uint32_t pkA[8][2], pkB[8][2], pkC[8][2], pkD[8][2];
  pred_l1(Wl, zfA, b1, l15, kg, pkA);
  pred_load(Hb, ia[2], ib[2], kg, gx, gy);  // C gathers overlap L1(B)
  pred_l1(Wl, zfB, b1, l15, kg, pkB);
  pred_load(Hb, ia[3], ib[3], kg, hx, hy);  // D gathers overlap cvt+L1(C)
  pred_cvt(gx, gy, zfC);
  pred_l1(Wl, zfC, b1, l15, kg, pkC);
  pred_cvt(hx, hy, zfD);
  pred_l1(Wl, zfD, b1, l15, kg, pkD);

  // ---- restage W2 ----
  __syncthreads();
  {
    const ushort_t* gp = W2 + sc * 128 + sh * 64;
#pragma unroll
    for (int gi = 0; gi < 8; ++gi) {
      int gg = sh * 8 + gi;
      uint4 v = *(const uint4*)(gp + gi * 8);
      *(uint4*)((char*)Wl + sc * 256 + ((gg ^ (sc & 7)) * 16)) = v;
    }
  }
  __syncthreads();

  // ---- layer 2 + dot per chunk ----
  float s;
  s = pred_l2(Wl, pkA, b2, w3, l15, kg);
  if (vv[0] && kg == 0) out[q0] = s + b3[0];
  s = pred_l2(Wl, pkB, b2, w3, l15, kg);
  if (vv[1] && kg == 0) out[q0 + 64] = s + b3[0];
  s = pred_l2(Wl, pkC, b2, w3, l15, kg);
  if (vv[2] && kg == 0) out[q0 + 128] = s + b3[0];
  s = pred_l2(Wl, pkD, b2, w3, l15, kg);
  if (vv[3] && kg == 0) out[q0 + 192] = s + b3[0];
}

// ---------------- launch ----------------

extern "C" void kernel_launch(void* const* d_in, const int* in_sizes, int n_in,
                              void* d_out, int out_size, void* d_ws, size_t ws_size,
                              hipStream_t stream) {
  const float* x = (const float*)d_in[0];
  const float* w = (const float*)d_in[1];
  const int* src = (const int*)d_in[2];
  const int* dst = (const int*)d_in[3];
  const int* pos_src = (const int*)d_in[4];
  const int* pos_dst = (const int*)d_in[5];
  const int* neg_src = (const int*)d_in[6];
  const int* neg_dst = (const int*)d_in[7];
  const float* W0 = (const float*)d_in[8];
  const float* b0 = (const float*)d_in[9];
  const float* W1 = (const float*)d_in[10];
  const float* b1 = (const float*)d_in[11];
  const float* W2 = (const float*)d_in[12];
  const float* b2 = (const float*)d_in[13];
  const float* Wp1 = (const float*)d_in[14];
  const float* bp1 = (const float*)d_in[15];
  const float* Wp2 = (const float*)d_in[16];
  const float* bp2 = (const float*)d_in[17];
  const float* Wp3 = (const float*)d_in[18];
  const float* bp3 = (const float*)d_in[19];

  const int N = in_sizes[0] / D128;
  const int E = in_sizes[1];
  const int P = in_sizes[4];

  float* out = (float*)d_out;
  float* h_fin = out + 2 * (size_t)P;   // [N,128] fp32 final h (d_out)
  uint32_t* Hp = (uint32_t*)h_fin;      // reused as hi/lo h1 scratch

  char* p = (char*)d_ws;
#define WALLOC(T, name, bytes) \
  T name = (T)p;               \
  p += (((size_t)(bytes) + 255) & ~(size_t)255);
  WALLOC(uint32_t*, meta, (size_t)(4 * 256 + 2 * 257) * 4)
  WALLOC(float*, deg_out, (size_t)N * 4)
  WALLOC(int*, rowptr, (size_t)(N + 1) * 4)
  WALLOC(uint2*, bufD, (size_t)E * 8)
  WALLOC(uint2*, bufS, (size_t)E * 8)
  WALLOC(uint2*, esw, (size_t)E * 8)
  WALLOC(ushort_t*, Wpk, (size_t)180224 * 2)
  WALLOC(uint32_t*, Xp, (size_t)N * D128 * 4)   // hi/lo: x, then h2
  WALLOC(uint32_t*, Xb, (size_t)N * 64 * 4)     // bf16 x
  WALLOC(uint32_t*, A, (size_t)N * 64 * 4)      // bf16 hop-1 result
  WALLOC(uint32_t*, B, (size_t)N * 64 * 4)      // bf16 hop-2 result / h3 plane
  WALLOC(uint32_t*, Hbuf, (size_t)N * 64 * 4)   // bf16 h1/h2 plane
#undef WALLOC

  uint32_t* histD = meta;
  uint32_t* histS = meta + 256;
  uint32_t* curD = meta + 512;
  uint32_t* curS = meta + 768;
  uint32_t* baseD = meta + 1024;
  uint32_t* baseS = meta + 1024 + 257;

  const ushort_t* W0b = Wpk;
  const ushort_t* W1b = Wpk + 49152;
  const ushort_t* W2b = Wpk + 98304;
  const ushort_t* Wp1b = Wpk + 147456;
  const ushort_t* Wp2b = Wpk + 163840;

  const int rb = (N + 3) / 4;
  const int gg = (N + 63) / 64;
  const int nHi = (N + 255) >> 8;
  const int n4 = N * 32;

  // ---- sort-based graph build ----
  hipMemsetAsync(meta, 0, 4 * 256 * 4, stream);
  k_hist2<<<128, 256, 0, stream>>>(src, dst, E, histD, histS);
  k_scan2<<<1, 256, 0, stream>>>(histD, histS, curD, baseD, curS, baseS, rowptr, N, E);
  k_part2<<<128, 256, 0, stream>>>(src, dst, w, E, curD, curS, bufD, bufS);
  k_sub2<<<nHi, 256, 0, stream>>>(bufD, baseD, bufS, baseS, esw, rowptr, deg_out, N);
  k_norm<<<rb, 256, 0, stream>>>(deg_out, rowptr, esw, N);

  // ---- pack inputs (features + weights, one kernel) ----
  k_packX<<<(n4 + 180224 + 255) / 256, 256, 0, stream>>>(x, Xp, Xb, n4, W0, W1, W2,
                                                         Wp1, Wp2, Wpk);

  // ---- layer 1: (Xp, Xb) -> h1 in (Hp hi/lo, Hbuf bf16) ----
  k_spmm<<<rb, 256, 0, stream>>>(Xb, A, esw, rowptr, N);
  k_spmm<<<rb, 256, 0, stream>>>(A, B, esw, rowptr, N);
  k_gemm<<<gg, 256, 0, stream>>>(Xp, A, B, W0b, b0, 1, N, Hp, (ushort_t*)Hbuf, nullptr);
  // ---- layer 2: (Hp, Hbuf) -> h2 in (Xp hi/lo, Hbuf bf16) ----
  k_spmm<<<rb, 256, 0, stream>>>(Hbuf, A, esw, rowptr, N);
  k_spmm<<<rb, 256, 0, stream>>>(A, B, esw, rowptr, N);
  k_gemm<<<gg, 256, 0, stream>>>(Hp, A, B, W1b, b1, 1, N, Xp, (ushort_t*)Hbuf, nullptr);
  // ---- layer 3: (Xp, Hbuf) -> h3 fp32 in h_fin + bf16 plane in B (alias) ----
  k_spmm<<<rb, 256, 0, stream>>>(Hbuf, A, esw, rowptr, N);
  k_spmm<<<rb, 256, 0, stream>>>(A, B, esw, rowptr, N);
  k_gemm<<<gg, 256, 0, stream>>>(Xp, A, B, W2b, b2, 0, N, nullptr, (ushort_t*)B, h_fin);

  // ---- fused predictor over pos+neg (2P pairs, 256/block) ----
  k_pred<<<(2 * P + 255) / 256, 256, 0, stream>>>(B, pos_src, pos_dst, neg_src, neg_dst,
                                                  Wp1b, Wp2b, bp1, bp2, Wp3, bp3, P, out);
}

// Round 14
// 417.880 us; speedup vs baseline: 1.0556x; 1.0556x over previous
//
#include <hip/hip_runtime.h>
#include <stdint.h>

// ---------------------------------------------------------------------------
// TAGConv(3 layers, K=2) + edge-weight norm + MLP link predictor.
// Round 14: revert k_pred to the R12 2-chunk version (4-chunk R13 blew VGPR
// 112->204, occupancy halved, 46.5->68.7us). Keep merged k_sub2/k_packX.
// Chunk-count sweep settled: 1=58us, 2=46.5us, 4=68.7us -> 2 is optimal.
// ---------------------------------------------------------------------------

#define D128 128

typedef __bf16 v8bf __attribute__((ext_vector_type(8)));
typedef float v4f __attribute__((ext_vector_type(4)));
typedef uint32_t v4u __attribute__((ext_vector_type(4)));
typedef unsigned short ushort_t;

union BFU { v4u u; v8bf b; uint4 q; };

__device__ __forceinline__ uint32_t pack_hl(float f) {
  uint32_t hi = __float_as_uint(f) & 0xffff0000u;
  float lo = f - __uint_as_float(hi);
  return hi | (__float_as_uint(lo) >> 16);
}
__device__ __forceinline__ uint32_t f2bf_rn(float f) {
  uint32_t u = __float_as_uint(f);
  return (u + 0x7fffu + ((u >> 16) & 1u)) >> 16;
}
__device__ __forceinline__ float bflo(uint32_t u) { return __uint_as_float(u << 16); }
__device__ __forceinline__ float bfhi(uint32_t u) { return __uint_as_float(u & 0xffff0000u); }
__device__ __forceinline__ uint32_t bfmul2(uint32_t a, uint32_t b) {
  return f2bf_rn(bflo(a) * bflo(b)) | (f2bf_rn(bfhi(a) * bfhi(b)) << 16);
}

// ---------------- sort-based graph build ------------------------------------

__global__ void k_hist2(const int* __restrict__ src, const int* __restrict__ dst,
                        int E, uint32_t* __restrict__ histD,
                        uint32_t* __restrict__ histS) {
  __shared__ uint32_t hd[256], hs[256];
  int t = threadIdx.x;
  hd[t] = 0; hs[t] = 0;
  __syncthreads();
  for (int e = blockIdx.x * 256 + t; e < E; e += gridDim.x * 256) {
    atomicAdd(&hd[((unsigned)dst[e]) >> 8], 1u);
    atomicAdd(&hs[((unsigned)src[e]) >> 8], 1u);
  }
  __syncthreads();
  if (hd[t]) atomicAdd(&histD[t], hd[t]);
  if (hs[t]) atomicAdd(&histS[t], hs[t]);
}

__global__ void k_scan2(const uint32_t* __restrict__ histD,
                        const uint32_t* __restrict__ histS,
                        uint32_t* __restrict__ curD, uint32_t* __restrict__ baseD,
                        uint32_t* __restrict__ curS, uint32_t* __restrict__ baseS,
                        int* __restrict__ rowptr, int N, int E) {
  __shared__ uint32_t ws[4];
  int t = threadIdx.x;
  int lane = t & 63, wid = t >> 6;
  for (int which = 0; which < 2; ++which) {
    uint32_t v = which ? histS[t] : histD[t];
    uint32_t x = v;
#pragma unroll
    for (int d = 1; d < 64; d <<= 1) {
      uint32_t y = (uint32_t)__shfl_up((int)x, d);
      if (lane >= d) x += y;
    }
    if (lane == 63) ws[wid] = x;
    __syncthreads();
    if (t == 0) {
      uint32_t a = 0;
#pragma unroll
      for (int k = 0; k < 4; ++k) { uint32_t tmp = ws[k]; ws[k] = a; a += tmp; }
    }
    __syncthreads();
    uint32_t ex = x - v + ws[wid];
    if (which == 0) {
      curD[t] = ex; baseD[t] = ex;
      if (t == 0) baseD[256] = (uint32_t)E;
    } else {
      curS[t] = ex; baseS[t] = ex;
      if (t == 0) baseS[256] = (uint32_t)E;
    }
    __syncthreads();
  }
  if (t == 0) rowptr[N] = E;
}

// merged partition: one pass over src/dst/w, both bucket sets
__global__ void k_part2(const int* __restrict__ src, const int* __restrict__ dst,
                        const float* __restrict__ w, int E,
                        uint32_t* __restrict__ curD, uint32_t* __restrict__ curS,
                        uint2* __restrict__ bufD, uint2* __restrict__ bufS) {
  __shared__ uint32_t lhD[256], lbD[256], lhS[256], lbS[256];
  int t = threadIdx.x;
  int per = (E + gridDim.x - 1) / gridDim.x;
  int e0 = blockIdx.x * per, e1 = min(e0 + per, E);
  lhD[t] = 0; lhS[t] = 0;
  __syncthreads();
  for (int e = e0 + t; e < e1; e += 256) {
    atomicAdd(&lhD[((unsigned)dst[e]) >> 8], 1u);
    atomicAdd(&lhS[((unsigned)src[e]) >> 8], 1u);
  }
  __syncthreads();
  uint32_t cD = lhD[t], cS = lhS[t];
  lbD[t] = cD ? atomicAdd(&curD[t], cD) : 0u;
  lbS[t] = cS ? atomicAdd(&curS[t], cS) : 0u;
  __syncthreads();
  lhD[t] = 0; lhS[t] = 0;
  __syncthreads();
  for (int e = e0 + t; e < e1; e += 256) {
    int s = src[e], d = dst[e];
    uint32_t wb = __float_as_uint(w[e]);
    uint32_t binD = ((unsigned)d) >> 8;
    uint32_t posD = lbD[binD] + atomicAdd(&lhD[binD], 1u);
    bufD[posD] = make_uint2((((unsigned)d & 255u) << 16) | (unsigned)s, wb);
    uint32_t binS = ((unsigned)s) >> 8;
    uint32_t posS = lbS[binS] + atomicAdd(&lhS[binS], 1u);
    bufS[posS] = make_uint2((unsigned)s, wb);
  }
}

// merged: per-bucket dst counting sort -> CSR, plus src LDS float bins -> deg_out
__global__ void k_sub2(const uint2* __restrict__ bufD, const uint32_t* __restrict__ baseD,
                       const uint2* __restrict__ bufS, const uint32_t* __restrict__ baseS,
                       uint2* __restrict__ esw, int* __restrict__ rowptr,
                       float* __restrict__ deg_out, int N) {
  __shared__ uint32_t lh[256], cur[256], ws4[4];
  __shared__ float facc[256];
  int hb = blockIdx.x, t = threadIdx.x;
  lh[t] = 0;
  facc[t] = 0.f;
  __syncthreads();
  int bS = (int)baseS[hb], eS = (int)baseS[hb + 1];
  for (int i = bS + t; i < eS; i += 256)
    atomicAdd(&facc[bufS[i].x & 255u], __uint_as_float(bufS[i].y));
  int b = (int)baseD[hb], e = (int)baseD[hb + 1];
  for (int i = b + t; i < e; i += 256) atomicAdd(&lh[(bufD[i].x >> 16) & 255u], 1u);
  __syncthreads();
  int s0 = hb * 256 + t;
  if (s0 < N) deg_out[s0] = facc[t];
  uint32_t v = lh[t], x = v;
  int lane = t & 63, wid = t >> 6;
#pragma unroll
  for (int d = 1; d < 64; d <<= 1) {
    uint32_t y = (uint32_t)__shfl_up((int)x, d);
    if (lane >= d) x += y;
  }
  if (lane == 63) ws4[wid] = x;
  __syncthreads();
  if (t == 0) {
    uint32_t a = 0;
#pragma unroll
    for (int k = 0; k < 4; ++k) { uint32_t tmp = ws4[k]; ws4[k] = a; a += tmp; }
  }
  __syncthreads();
  uint32_t ex = x - v + ws4[wid];
  cur[t] = ex;
  if (s0 < N) rowptr[s0] = b + (int)ex;
  __syncthreads();
  for (int i = b + t; i < e; i += 256) {
    uint2 el = bufD[i];
    uint32_t lo = (el.x >> 16) & 255u;
    uint32_t pos = atomicAdd(&cur[lo], 1u);
    esw[b + pos] = make_uint2(el.x & 0xffffu, el.y);
  }
}

__global__ void k_norm(const float* __restrict__ deg_out, const int* __restrict__ rowptr,
                       uint2* __restrict__ esw, int n) {
  int row = blockIdx.x * 4 + (threadIdx.x >> 6);
  if (row >= n) return;
  int lane = threadIdx.x & 63;
  int b0 = rowptr[row];
  int cnt = rowptr[row + 1] - b0;
  if (cnt <= 64) {
    uint32_t key = 0xffffffffu;
    float val = 0.f;
    if (lane < cnt) {
      uint2 e = esw[b0 + lane];
      key = e.x;
      val = __uint_as_float(e.y);
    }
    float s = val;
#pragma unroll
    for (int d = 32; d; d >>= 1) s += __shfl_xor(s, d);
#pragma unroll
    for (int k = 2; k <= 64; k <<= 1) {
#pragma unroll
      for (int j = k >> 1; j > 0; j >>= 1) {
        uint32_t ok = (uint32_t)__shfl_xor((int)key, j);
        float ov = __shfl_xor(val, j);
        bool asc = ((lane & k) == 0);
        bool lower = ((lane & j) == 0);
        bool take_min = (lower == asc);
        bool sw = take_min ? (ok < key) : (ok > key);
        if (sw) { key = ok; val = ov; }
      }
    }
    if (lane < cnt) {
      float dout = deg_out[key];
      float nw = val / sqrtf(fmaxf(dout * s, 1e-12f));
      esw[b0 + lane] = make_uint2(key, __float_as_uint(nw));
    }
  } else {
    float s = 0.f;
    for (int i = lane; i < cnt; i += 64) s += __uint_as_float(esw[b0 + i].y);
#pragma unroll
    for (int d = 32; d; d >>= 1) s += __shfl_xor(s, d);
    for (int i = lane; i < cnt; i += 64) {
      uint2 e = esw[b0 + i];
      float dout = deg_out[e.x];
      float nw = __uint_as_float(e.y) / sqrtf(fmaxf(dout * s, 1e-12f));
      esw[b0 + i] = make_uint2(e.x, __float_as_uint(nw));
    }
  }
}

// ---------------- format conversion (merged features + weights) -------------

__global__ void k_packX(const float* __restrict__ xin, uint32_t* __restrict__ Xp,
                        uint32_t* __restrict__ Xb, int n4,
                        const float* __restrict__ p0, const float* __restrict__ p1,
                        const float* __restrict__ p2, const float* __restrict__ p3,
                        const float* __restrict__ p4, ushort_t* __restrict__ outW) {
  int i = blockIdx.x * 256 + threadIdx.x;
  if (i < n4) {
    float4 f = ((const float4*)xin)[i];
    ((uint4*)Xp)[i] = make_uint4(pack_hl(f.x), pack_hl(f.y), pack_hl(f.z), pack_hl(f.w));
    uint2 b;
    b.x = f2bf_rn(f.x) | (f2bf_rn(f.y) << 16);
    b.y = f2bf_rn(f.z) | (f2bf_rn(f.w) << 16);
    ((uint2*)Xb)[i] = b;
  } else {
    int j = i - n4;
    if (j < 180224) {
      float f;
      if (j < 49152) f = p0[j];
      else if (j < 98304) f = p1[j - 49152];
      else if (j < 147456) f = p2[j - 98304];
      else if (j < 163840) f = p3[j - 147456];
      else f = p4[j - 163840];
      outW[j] = (ushort_t)f2bf_rn(f);
    }
  }
}

// ---------------- SpMM: CSR, 16-deep gather batches -------------------------

__global__ __launch_bounds__(256) void k_spmm(
    const uint32_t* __restrict__ X, uint32_t* __restrict__ Y,
    const uint2* __restrict__ esw, const int* __restrict__ rowptr, int n) {
  int row = blockIdx.x * 4 + (threadIdx.x >> 6);
  if (row >= n) return;
  row = __builtin_amdgcn_readfirstlane(row);
  int lane = threadIdx.x & 63;
  int b0 = rowptr[row];
  int cnt = rowptr[row + 1] - b0;
  const uint2* __restrict__ ep = esw + b0;
  const uint32_t* __restrict__ Xl = X + lane;
  float a0 = 0.f, a1 = 0.f, c0 = 0.f, c1 = 0.f;
  int i = 0;
  for (; i + 16 <= cnt; i += 16) {
    uint2 e[16];
#pragma unroll
    for (int j = 0; j < 16; ++j) e[j] = ep[i + j];
    uint32_t u[16];
#pragma unroll
    for (int j = 0; j < 16; ++j) u[j] = Xl[(size_t)e[j].x * 64];
#pragma unroll
    for (int j = 0; j < 16; j += 2) {
      float w0 = __uint_as_float(e[j].y);
      float w1 = __uint_as_float(e[j + 1].y);
      a0 = fmaf(w0, bflo(u[j]), a0);
      a1 = fmaf(w0, bfhi(u[j]), a1);
      c0 = fmaf(w1, bflo(u[j + 1]), c0);
      c1 = fmaf(w1, bfhi(u[j + 1]), c1);
    }
  }
  for (; i + 4 <= cnt; i += 4) {
    uint2 e[4];
#pragma unroll
    for (int j = 0; j < 4; ++j) e[j] = ep[i + j];
    uint32_t u[4];
#pragma unroll
    for (int j = 0; j < 4; ++j) u[j] = Xl[(size_t)e[j].x * 64];
#pragma unroll
    for (int j = 0; j < 4; j += 2) {
      float w0 = __uint_as_float(e[j].y);
      float w1 = __uint_as_float(e[j + 1].y);
      a0 = fmaf(w0, bflo(u[j]), a0);
      a1 = fmaf(w0, bfhi(u[j]), a1);
      c0 = fmaf(w1, bflo(u[j + 1]), c0);
      c1 = fmaf(w1, bfhi(u[j + 1]), c1);
    }
  }
  for (; i < cnt; ++i) {
    uint2 e = ep[i];
    uint32_t u = Xl[(size_t)e.x * 64];
    float w0 = __uint_as_float(e.y);
    a0 = fmaf(w0, bflo(u), a0);
    a1 = fmaf(w0, bfhi(u), a1);
  }
  Y[(size_t)row * 64 + lane] = f2bf_rn(a0 + c0) | (f2bf_rn(a1 + c1) << 16);
}

// ---------------- MFMA GEMM --------------------------------------------------

__device__ __forceinline__ void build_frags_v(uint4 q0, uint4 q1, v8bf& hi, v8bf& lo) {
  BFU uh, ul;
  uh.u[0] = (q0.x >> 16) | (q0.y & 0xffff0000u);
  uh.u[1] = (q0.z >> 16) | (q0.w & 0xffff0000u);
  uh.u[2] = (q1.x >> 16) | (q1.y & 0xffff0000u);
  uh.u[3] = (q1.z >> 16) | (q1.w & 0xffff0000u);
  ul.u[0] = (q0.x & 0xffffu) | (q0.y << 16);
  ul.u[1] = (q0.z & 0xffffu) | (q0.w << 16);
  ul.u[2] = (q1.x & 0xffffu) | (q1.y << 16);
  ul.u[3] = (q1.z & 0xffffu) | (q1.w << 16);
  hi = uh.b;
  lo = ul.b;
}

__global__ __launch_bounds__(256) void k_gemm(
    const uint32_t* __restrict__ F0hl, const uint32_t* __restrict__ F1b,
    const uint32_t* __restrict__ F2b, const ushort_t* __restrict__ Wb,
    const float* __restrict__ bias, int relu, int M,
    uint32_t* __restrict__ outp, ushort_t* __restrict__ outh,
    float* __restrict__ outf) {
  __shared__ ushort_t Wl[128 * 128];  // 32 KB swizzled
  const int t = threadIdx.x;
  const int lane = t & 63;
  const int wave = t >> 6;
  const int wr = wave >> 1, wc = wave & 1;
  const int row0 = blockIdx.x * 64;
  const int l15 = lane & 15;
  const int kg = lane >> 4;

  int arow[2];
#pragma unroll
  for (int mr = 0; mr < 2; ++mr)
    arow[mr] = min(row0 + wr * 32 + mr * 16 + l15, M - 1);
  int wcol[4];
  float bv[4];
#pragma unroll
  for (int nr = 0; nr < 4; ++nr) {
    wcol[nr] = wc * 64 + nr * 16 + l15;
    bv[nr] = bias[wcol[nr]];
  }

  const uint32_t* __restrict__ F0r0 = F0hl + (size_t)arow[0] * D128 + kg * 8;
  const uint32_t* __restrict__ F0r1 = F0hl + (size_t)arow[1] * D128 + kg * 8;
  const uint32_t* __restrict__ F1r0 = F1b + (size_t)arow[0] * 64 + kg * 4;
  const uint32_t* __restrict__ F1r1 = F1b + (size_t)arow[1] * 64 + kg * 4;
  const uint32_t* __restrict__ F2r0 = F2b + (size_t)arow[0] * 64 + kg * 4;
  const uint32_t* __restrict__ F2r1 = F2b + (size_t)arow[1] * 64 + kg * 4;

  v4f acc[2][4];
#pragma unroll
  for (int mr = 0; mr < 2; ++mr)
#pragma unroll
    for (int nr = 0; nr < 4; ++nr) acc[mr][nr] = (v4f){0.f, 0.f, 0.f, 0.f};

  const int sc = t >> 1;
  const int sh = t & 1;
  const ushort_t* gpW = Wb + (size_t)sc * 384 + sh * 64;
  char* WlBase = (char*)Wl + sc * 256;

  // ---------------- seg0 (hi/lo plane, 2 MFMA per frag) ----------------
  uint4 f0[4][2][2];
#pragma unroll
  for (int kc = 0; kc < 2; ++kc) {
    f0[kc][0][0] = *(const uint4*)(F0r0 + kc * 32);
    f0[kc][0][1] = *(const uint4*)(F0r0 + kc * 32 + 4);
    f0[kc][1][0] = *(const uint4*)(F0r1 + kc * 32);
    f0[kc][1][1] = *(const uint4*)(F0r1 + kc * 32 + 4);
  }
  __syncthreads();
  {
    const ushort_t* gp = gpW;
#pragma unroll
    for (int gi = 0; gi < 8; ++gi) {
      int gg = sh * 8 + gi;
      uint4 v = *(const uint4*)(gp + gi * 8);
      *(uint4*)(WlBase + ((gg ^ (sc & 7)) * 16)) = v;
    }
  }
  __syncthreads();
#pragma unroll
  for (int kc = 0; kc < 4; ++kc) {
    if (kc < 2) {
      f0[kc + 2][0][0] = *(const uint4*)(F0r0 + (kc + 2) * 32);
      f0[kc + 2][0][1] = *(const uint4*)(F0r0 + (kc + 2) * 32 + 4);
      f0[kc + 2][1][0] = *(const uint4*)(F0r1 + (kc + 2) * 32);
      f0[kc + 2][1][1] = *(const uint4*)(F0r1 + (kc + 2) * 32 + 4);
    }
    v8bf ah[2], al[2];
#pragma unroll
    for (int mr = 0; mr < 2; ++mr)
      build_frags_v(f0[kc][mr][0], f0[kc][mr][1], ah[mr], al[mr]);
#pragma unroll
    for (int nr = 0; nr < 4; ++nr) {
      int col = wcol[nr];
      int g = (kc << 2) + kg;
      v8bf bf = *(const v8bf*)((const char*)Wl + col * 256 + ((g ^ (col & 7)) * 16));
#pragma unroll
      for (int mr = 0; mr < 2; ++mr) {
        acc[mr][nr] = __builtin_amdgcn_mfma_f32_16x16x32_bf16(ah[mr], bf, acc[mr][nr], 0, 0, 0);
        acc[mr][nr] = __builtin_amdgcn_mfma_f32_16x16x32_bf16(al[mr], bf, acc[mr][nr], 0, 0, 0);
      }
    }
  }

  // ---------------- seg1, seg2 (bf16 planes, full preload) ----------------
#pragma unroll
  for (int seg = 1; seg < 3; ++seg) {
    const uint32_t* __restrict__ Fr0 = (seg == 1) ? F1r0 : F2r0;
    const uint32_t* __restrict__ Fr1 = (seg == 1) ? F1r1 : F2r1;
    uint4 fb[4][2];
#pragma unroll
    for (int kc = 0; kc < 4; ++kc) {
      fb[kc][0] = *(const uint4*)(Fr0 + kc * 16);
      fb[kc][1] = *(const uint4*)(Fr1 + kc * 16);
    }
    __syncthreads();
    {
      const ushort_t* gp = gpW + seg * 128;
#pragma unroll
      for (int gi = 0; gi < 8; ++gi) {
        int gg = sh * 8 + gi;
        uint4 v = *(const uint4*)(gp + gi * 8);
        *(uint4*)(WlBase + ((gg ^ (sc & 7)) * 16)) = v;
      }
    }
    __syncthreads();
#pragma unroll
    for (int kc = 0; kc < 4; ++kc) {
      v8bf af[2];
      {
        BFU u0, u1;
        u0.q = fb[kc][0];
        u1.q = fb[kc][1];
        af[0] = u0.b;
        af[1] = u1.b;
      }
#pragma unroll
      for (int nr = 0; nr < 4; ++nr) {
        int col = wcol[nr];
        int g = (kc << 2) + kg;
        v8bf bf = *(const v8bf*)((const char*)Wl + col * 256 + ((g ^ (col & 7)) * 16));
#pragma unroll
        for (int mr = 0; mr < 2; ++mr)
          acc[mr][nr] = __builtin_amdgcn_mfma_f32_16x16x32_bf16(af[mr], bf, acc[mr][nr], 0, 0, 0);
      }
    }
  }

  __syncthreads();  // all reads done before (possibly aliased) epilogue writes

#pragma unroll
  for (int mr = 0; mr < 2; ++mr) {
#pragma unroll
    for (int nr = 0; nr < 4; ++nr) {
      v4f a = acc[mr][nr];
#pragma unroll
      for (int r = 0; r < 4; ++r) {
        int row = row0 + wr * 32 + mr * 16 + kg * 4 + r;
        if (row < M) {
          float v = a[r] + bv[nr];
          if (relu) v = fmaxf(v, 0.f);
          size_t o = (size_t)row * D128 + wcol[nr];
          if (outp) outp[o] = pack_hl(v);
          if (outh) outh[o] = (ushort_t)f2bf_rn(v);
          if (outf) outf[o] = v;
        }
      }
    }
  }
}

// ---------------- fused predictor (128 pairs/block, 2 chunks) ----------------

__global__ __launch_bounds__(256) void k_pred(
    const uint32_t* __restrict__ Hb, const int* __restrict__ pos_src,
    const int* __restrict__ pos_dst, const int* __restrict__ neg_src,
    const int* __restrict__ neg_dst, const ushort_t* __restrict__ W1,
    const ushort_t* __restrict__ W2, const float* __restrict__ b1,
    const float* __restrict__ b2, const float* __restrict__ w3,
    const float* __restrict__ b3, int P, float* __restrict__ out) {
  __shared__ ushort_t Wl[128 * 128];
  const int t = threadIdx.x;
  const int lane = t & 63;
  const int wave = t >> 6;
  const int l15 = lane & 15;
  const int kg = lane >> 4;
  const int P2 = 2 * P;

  const int qA = blockIdx.x * 128 + wave * 16 + l15;
  const int qB = qA + 64;
  const bool vA = qA < P2, vB = qB < P2;
  const int qcA = vA ? qA : (P2 - 1);
  const int qcB = vB ? qB : (P2 - 1);
  const int iaA = (qcA < P) ? pos_src[qcA] : neg_src[qcA - P];
  const int ibA = (qcA < P) ? pos_dst[qcA] : neg_dst[qcA - P];
  const int iaB = (qcB < P) ? pos_src[qcB] : neg_src[qcB - P];
  const int ibB = (qcB < P) ? pos_dst[qcB] : neg_dst[qcB - P];

  const int sc = t >> 1;
  const int sh = t & 1;

  // ---- stage W1 ----
  {
    const ushort_t* gp = W1 + sc * 128 + sh * 64;
#pragma unroll
    for (int gi = 0; gi < 8; ++gi) {
      int gg = sh * 8 + gi;
      uint4 v = *(const uint4*)(gp + gi * 8);
      *(uint4*)((char*)Wl + sc * 256 + ((gg ^ (sc & 7)) * 16)) = v;
    }
  }

  // ---- gather both chunks (32 independent 16B loads in flight) ----
  uint4 gaA[4], gbA[4], gaB[4], gbB[4];
#pragma unroll
  for (int kc = 0; kc < 4; ++kc) {
    gaA[kc] = *(const uint4*)(Hb + (size_t)iaA * 64 + kc * 16 + kg * 4);
    gbA[kc] = *(const uint4*)(Hb + (size_t)ibA * 64 + kc * 16 + kg * 4);
    gaB[kc] = *(const uint4*)(Hb + (size_t)iaB * 64 + kc * 16 + kg * 4);
    gbB[kc] = *(const uint4*)(Hb + (size_t)ibB * 64 + kc * 16 + kg * 4);
  }
  v8bf zfA[4], zfB[4];
#pragma unroll
  for (int kc = 0; kc < 4; ++kc) {
    BFU zA, zB;
    zA.u[0] = bfmul2(gaA[kc].x, gbA[kc].x);
    zA.u[1] = bfmul2(gaA[kc].y, gbA[kc].y);
    zA.u[2] = bfmul2(gaA[kc].z, gbA[kc].z);
    zA.u[3] = bfmul2(gaA[kc].w, gbA[kc].w);
    zB.u[0] = bfmul2(gaB[kc].x, gbB[kc].x);
    zB.u[1] = bfmul2(gaB[kc].y, gbB[kc].y);
    zB.u[2] = bfmul2(gaB[kc].z, gbB[kc].z);
    zB.u[3] = bfmul2(gaB[kc].w, gbB[kc].w);
    zfA[kc] = zA.b;
    zfB[kc] = zB.b;
  }
  __syncthreads();

  // ---- layer 1, chunk A then chunk B ----
  uint32_t pkA[8][2], pkB[8][2];
  {
    v4f acc1[8];
#pragma unroll
    for (int nr = 0; nr < 8; ++nr) acc1[nr] = (v4f){0.f, 0.f, 0.f, 0.f};
#pragma unroll
    for (int kc = 0; kc < 4; ++kc) {
#pragma unroll
      for (int nr = 0; nr < 8; ++nr) {
        int c = nr * 16 + l15;
        int g = 4 * kc + kg;
        v8bf wf = *(const v8bf*)((const char*)Wl + c * 256 + ((g ^ (c & 7)) * 16));
        acc1[nr] = __builtin_amdgcn_mfma_f32_16x16x32_bf16(wf, zfA[kc], acc1[nr], 0, 0, 0);
      }
    }
#pragma unroll
    for (int nr = 0; nr < 8; ++nr) {
      float v0 = fmaxf(acc1[nr][0] + b1[nr * 16 + kg * 4 + 0], 0.f);
      float v1 = fmaxf(acc1[nr][1] + b1[nr * 16 + kg * 4 + 1], 0.f);
      float v2 = fmaxf(acc1[nr][2] + b1[nr * 16 + kg * 4 + 2], 0.f);
      float v3 = fmaxf(acc1[nr][3] + b1[nr * 16 + kg * 4 + 3], 0.f);
      pkA[nr][0] = f2bf_rn(v0) | (f2bf_rn(v1) << 16);
      pkA[nr][1] = f2bf_rn(v2) | (f2bf_rn(v3) << 16);
    }
  }
  {
    v4f acc1[8];
#pragma unroll
    for (int nr = 0; nr < 8; ++nr) acc1[nr] = (v4f){0.f, 0.f, 0.f, 0.f};
#pragma unroll
    for (int kc = 0; kc < 4; ++kc) {
#pragma unroll
      for (int nr = 0; nr < 8; ++nr) {
        int c = nr * 16 + l15;
        int g = 4 * kc + kg;
        v8bf wf = *(const v8bf*)((const char*)Wl + c * 256 + ((g ^ (c & 7)) * 16));
        acc1[nr] = __builtin_amdgcn_mfma_f32_16x16x32_bf16(wf, zfB[kc], acc1[nr], 0, 0, 0);
      }
    }
#pragma unroll
    for (int nr = 0; nr < 8; ++nr) {
      float v0 = fmaxf(acc1[nr][0] + b1[nr * 16 + kg * 4 + 0], 0.f);
      float v1 = fmaxf(acc1[nr][1] + b1[nr * 16 + kg * 4 + 1], 0.f);
      float v2 = fmaxf(acc1[nr][2] + b1[nr * 16 + kg * 4 + 2], 0.f);
      float v3 = fmaxf(acc1[nr][3] + b1[nr * 16 + kg * 4 + 3], 0.f);
      pkB[nr][0] = f2bf_rn(v0) | (f2bf_rn(v1) << 16);
      pkB[nr][1] = f2bf_rn(v2) | (f2bf_rn(v3) << 16);
    }
  }

  // ---- restage W2 ----
  __syncthreads();
  {
    const ushort_t* gp = W2 + sc * 128 + sh * 64;
#pragma unroll
    for (int gi = 0; gi < 8; ++gi) {
      int gg = sh * 8 + gi;
      uint4 v = *(const uint4*)(gp + gi * 8);
      *(uint4*)((char*)Wl + sc * 256 + ((gg ^ (sc & 7)) * 16)) = v;
    }
  }
  __syncthreads();

  // ---- layer 2 + dot, chunk A then chunk B ----
#pragma unroll
  for (int chunk = 0; chunk < 2; ++chunk) {
    v4f acc2[8];
#pragma unroll
    for (int nr = 0; nr < 8; ++nr) acc2[nr] = (v4f){0.f, 0.f, 0.f, 0.f};
#pragma unroll
    for (int kc = 0; kc < 4; ++kc) {
      BFU y;
#pragma unroll
      for (int d = 0; d < 4; ++d) {
        int srcLane = l15 + 16 * ((kg & 1) * 2 + (d >> 1));
        uint32_t w0, w1;
        if (chunk == 0) {
          w0 = (uint32_t)__shfl((int)pkA[2 * kc][d & 1], srcLane);
          w1 = (uint32_t)__shfl((int)pkA[2 * kc + 1][d & 1], srcLane);
        } else {
          w0 = (uint32_t)__shfl((int)pkB[2 * kc][d & 1], srcLane);
          w1 = (uint32_t)__shfl((int)pkB[2 * kc + 1][d & 1], srcLane);
        }
        y.u[d] = (kg & 2) ? w1 : w0;
      }
#pragma unroll
      for (int nr = 0; nr < 8; ++nr) {
        int c = nr * 16 + l15;
        int g = 4 * kc + kg;
        v8bf wf = *(const v8bf*)((const char*)Wl + c * 256 + ((g ^ (c & 7)) * 16));
        acc2[nr] = __builtin_amdgcn_mfma_f32_16x16x32_bf16(wf, y.b, acc2[nr], 0, 0, 0);
      }
    }
    float s = 0.f;
#pragma unroll
    for (int nr = 0; nr < 8; ++nr) {
#pragma unroll
      for (int r = 0; r < 4; ++r) {
        int c = nr * 16 + kg * 4 + r;
        s += fmaxf(acc2[nr][r] + b2[c], 0.f) * w3[c];
      }
    }
    s += __shfl_xor(s, 16);
    s += __shfl_xor(s, 32);
    if (chunk == 0) {
      if (vA && kg == 0) out[qA] = s + b3[0];
    } else {
      if (vB && kg == 0) out[qB] = s + b3[0];
    }
  }
}

// ---------------- launch ----------------

extern "C" void kernel_launch(void* const* d_in, const int* in_sizes, int n_in,
                              void* d_out, int out_size, void* d_ws, size_t ws_size,
                              hipStream_t stream) {
  const float* x = (const float*)d_in[0];
  const float* w = (const float*)d_in[1];
  const int* src = (const int*)d_in[2];
  const int* dst = (const int*)d_in[3];
  const int* pos_src = (const int*)d_in[4];
  const int* pos_dst = (const int*)d_in[5];
  const int* neg_src = (const int*)d_in[6];
  const int* neg_dst = (const int*)d_in[7];
  const float* W0 = (const float*)d_in[8];
  const float* b0 = (const float*)d_in[9];
  const float* W1 = (const float*)d_in[10];
  const float* b1 = (const float*)d_in[11];
  const float* W2 = (const float*)d_in[12];
  const float* b2 = (const float*)d_in[13];
  const float* Wp1 = (const float*)d_in[14];
  const float* bp1 = (const float*)d_in[15];
  const float* Wp2 = (const float*)d_in[16];
  const float* bp2 = (const float*)d_in[17];
  const float* Wp3 = (const float*)d_in[18];
  const float* bp3 = (const float*)d_in[19];

  const int N = in_sizes[0] / D128;
  const int E = in_sizes[1];
  const int P = in_sizes[4];

  float* out = (float*)d_out;
  float* h_fin = out + 2 * (size_t)P;   // [N,128] fp32 final h (d_out)
  uint32_t* Hp = (uint32_t*)h_fin;      // reused as hi/lo h1 scratch

  char* p = (char*)d_ws;
#define WALLOC(T, name, bytes) \
  T name = (T)p;               \
  p += (((size_t)(bytes) + 255) & ~(size_t)255);
  WALLOC(uint32_t*, meta, (size_t)(4 * 256 + 2 * 257) * 4)
  WALLOC(float*, deg_out, (size_t)N * 4)
  WALLOC(int*, rowptr, (size_t)(N + 1) * 4)
  WALLOC(uint2*, bufD, (size_t)E * 8)
  WALLOC(uint2*, bufS, (size_t)E * 8)
  WALLOC(uint2*, esw, (size_t)E * 8)
  WALLOC(ushort_t*, Wpk, (size_t)180224 * 2)
  WALLOC(uint32_t*, Xp, (size_t)N * D128 * 4)   // hi/lo: x, then h2
  WALLOC(uint32_t*, Xb, (size_t)N * 64 * 4)     // bf16 x
  WALLOC(uint32_t*, A, (size_t)N * 64 * 4)      // bf16 hop-1 result
  WALLOC(uint32_t*, B, (size_t)N * 64 * 4)      // bf16 hop-2 result / h3 plane
  WALLOC(uint32_t*, Hbuf, (size_t)N * 64 * 4)   // bf16 h1/h2 plane
#undef WALLOC

  uint32_t* histD = meta;
  uint32_t* histS = meta + 256;
  uint32_t* curD = meta + 512;
  uint32_t* curS = meta + 768;
  uint32_t* baseD = meta + 1024;
  uint32_t* baseS = meta + 1024 + 257;

  const ushort_t* W0b = Wpk;
  const ushort_t* W1b = Wpk + 49152;
  const ushort_t* W2b = Wpk + 98304;
  const ushort_t* Wp1b = Wpk + 147456;
  const ushort_t* Wp2b = Wpk + 163840;

  const int rb = (N + 3) / 4;
  const int gg = (N + 63) / 64;
  const int nHi = (N + 255) >> 8;
  const int n4 = N * 32;

  // ---- sort-based graph build ----
  hipMemsetAsync(meta, 0, 4 * 256 * 4, stream);
  k_hist2<<<128, 256, 0, stream>>>(src, dst, E, histD, histS);
  k_scan2<<<1, 256, 0, stream>>>(histD, histS, curD, baseD, curS, baseS, rowptr, N, E);
  k_part2<<<128, 256, 0, stream>>>(src, dst, w, E, curD, curS, bufD, bufS);
  k_sub2<<<nHi, 256, 0, stream>>>(bufD, baseD, bufS, baseS, esw, rowptr, deg_out, N);
  k_norm<<<rb, 256, 0, stream>>>(deg_out, rowptr, esw, N);

  // ---- pack inputs (features + weights, one kernel) ----
  k_packX<<<(n4 + 180224 + 255) / 256, 256, 0, stream>>>(x, Xp, Xb, n4, W0, W1, W2,
                                                         Wp1, Wp2, Wpk);

  // ---- layer 1: (Xp, Xb) -> h1 in (Hp hi/lo, Hbuf bf16) ----
  k_spmm<<<rb, 256, 0, stream>>>(Xb, A, esw, rowptr, N);
  k_spmm<<<rb, 256, 0, stream>>>(A, B, esw, rowptr, N);
  k_gemm<<<gg, 256, 0, stream>>>(Xp, A, B, W0b, b0, 1, N, Hp, (ushort_t*)Hbuf, nullptr);
  // ---- layer 2: (Hp, Hbuf) -> h2 in (Xp hi/lo, Hbuf bf16) ----
  k_spmm<<<rb, 256, 0, stream>>>(Hbuf, A, esw, rowptr, N);
  k_spmm<<<rb, 256, 0, stream>>>(A, B, esw, rowptr, N);
  k_gemm<<<gg, 256, 0, stream>>>(Hp, A, B, W1b, b1, 1, N, Xp, (ushort_t*)Hbuf, nullptr);
  // ---- layer 3: (Xp, Hbuf) -> h3 fp32 in h_fin + bf16 plane in B (alias) ----
  k_spmm<<<rb, 256, 0, stream>>>(Hbuf, A, esw, rowptr, N);
  k_spmm<<<rb, 256, 0, stream>>>(A, B, esw, rowptr, N);
  k_gemm<<<gg, 256, 0, stream>>>(Xp, A, B, W2b, b2, 0, N, nullptr, (ushort_t*)B, h_fin);

  // ---- fused predictor over pos+neg (2P pairs, 128/block) ----
  k_pred<<<(2 * P + 127) / 128, 256, 0, stream>>>(B, pos_src, pos_dst, neg_src, neg_dst,
                                                  Wp1b, Wp2b, bp1, bp2, Wp3, bp3, P, out);
}